// Round 9
// baseline (492.900 us; speedup 1.0000x reference)
//
#include <hip/hip_runtime.h>

// Problem constants
#define BB 2
#define SS 2048
#define DD 1024
#define HH 16
#define DHH 64
#define DFF 4096
#define MM (BB * SS)   // 4096

typedef unsigned short u16;
typedef short short8 __attribute__((ext_vector_type(8)));
typedef float f32x4 __attribute__((ext_vector_type(4)));

__device__ __forceinline__ float b2f(u16 u) {
    return __uint_as_float(((unsigned)u) << 16);
}
__device__ __forceinline__ u16 f2b(float f) {
    unsigned u = __float_as_uint(f);
    unsigned r = (u + 0x7fffu + ((u >> 16) & 1u)) >> 16;  // RNE
    return (u16)r;
}
__device__ __forceinline__ float gelu_tanh_f(float x) {
    float x3 = x * x * x;
    float t = 0.7978845608028654f * (x + 0.044715f * x3);
    return 0.5f * x * (1.0f + tanhf(t));
}
// async 16B global -> LDS (wave-uniform LDS base + lane*16)
__device__ __forceinline__ void cp16(const u16* g, u16* l) {
    __builtin_amdgcn_global_load_lds(
        (const __attribute__((address_space(1))) void*)g,
        (__attribute__((address_space(3))) void*)l, 16, 0, 0);
}

// ---------------------------------------------------------------------------
// Weight convert+transpose tile: W f32 [K,N] -> WT bf16 [N,K], 64x64.
// ---------------------------------------------------------------------------
__device__ __forceinline__ void wconv_tile(const float* __restrict__ W,
                                           u16* __restrict__ WT,
                                           int Kdim, int Ndim, int gk, int gn,
                                           float (*tile)[65], int t) {
    const int k0 = gk * 64, n0 = gn * 64;
    const int c = t & 63, r0 = (t >> 6) * 16;
#pragma unroll
    for (int i = 0; i < 16; ++i)
        tile[r0 + i][c] = W[(size_t)(k0 + r0 + i) * Ndim + n0 + c];
    __syncthreads();
    const int k4 = (t & 15) * 4, nr = t >> 4;
#pragma unroll
    for (int i = 0; i < 4; ++i) {
        int n = nr + 16 * i;
        ushort4 u = {f2b(tile[k4 + 0][n]), f2b(tile[k4 + 1][n]),
                     f2b(tile[k4 + 2][n]), f2b(tile[k4 + 3][n])};
        *(ushort4*)&WT[(size_t)(n0 + n) * Kdim + k0 + k4] = u;
    }
}

// Fused upfront conversions: wq/wk/wv -> qkvT, w2 -> w2T. 1792 blocks.
__global__ __launch_bounds__(256) void wconvA(const float* __restrict__ wq,
                                              const float* __restrict__ wk,
                                              const float* __restrict__ wv,
                                              const float* __restrict__ w2,
                                              u16* __restrict__ qkvT,
                                              u16* __restrict__ w2T) {
    __shared__ float tile[64][65];
    const int bid = blockIdx.x, t = threadIdx.x;
    if (bid < 768) {
        const int r = bid >> 8, li = bid & 255;
        const float* W = (r == 0) ? wq : ((r == 1) ? wk : wv);
        wconv_tile(W, qkvT + (size_t)r * 1048576, DD, DD, li & 15, li >> 4, tile, t);
    } else {
        const int li = bid - 768;   // 0..1023; K=4096(64 tiles), N=1024(16)
        wconv_tile(w2, w2T, DFF, DD, li & 63, li >> 6, tile, t);
    }
}

// Deferred conversions (after attention merge frees their regions):
// wo -> woT, w1 -> w1T. 1280 blocks.
__global__ __launch_bounds__(256) void wconvB(const float* __restrict__ wo,
                                              const float* __restrict__ w1,
                                              u16* __restrict__ woT,
                                              u16* __restrict__ w1T) {
    __shared__ float tile[64][65];
    const int bid = blockIdx.x, t = threadIdx.x;
    if (bid < 256) {
        wconv_tile(wo, woT, DD, DD, bid & 15, bid >> 4, tile, t);
    } else {
        const int li = bid - 256;   // 0..1023; K=1024(16 tiles), N=4096(64)
        wconv_tile(w1, w1T, DD, DFF, li & 15, li >> 4, tile, t);
    }
}

// bias pack: [bq|bk|bv] -> 3072 f32
__global__ __launch_bounds__(256) void pack3(const float* __restrict__ a,
                                             const float* __restrict__ b,
                                             const float* __restrict__ c,
                                             float* __restrict__ o) {
    int i = blockIdx.x * 256 + threadIdx.x;
    o[i] = (i < 1024) ? a[i] : ((i < 2048) ? b[i - 1024] : c[i - 2048]);
}

// ---------------------------------------------------------------------------
// LayerNorm: one block per row of 1024. ddof=1 variance, eps added to std.
// ---------------------------------------------------------------------------
template <typename TI>
__global__ __launch_bounds__(256) void ln_kernel(const TI* __restrict__ x,
                                                 const float* __restrict__ g,
                                                 const float* __restrict__ bb,
                                                 u16* __restrict__ out) {
    __shared__ float red[8];
    const int row = blockIdx.x;
    const int t = threadIdx.x;
    const size_t base = (size_t)row * DD;

    float xv[4];
#pragma unroll
    for (int i = 0; i < 4; ++i) {
        int j = t + i * 256;
        if constexpr (sizeof(TI) == 2) xv[i] = b2f(((const u16*)x)[base + j]);
        else                            xv[i] = ((const float*)x)[base + j];
    }

    float part = xv[0] + xv[1] + xv[2] + xv[3];
#pragma unroll
    for (int off = 32; off > 0; off >>= 1) part += __shfl_xor(part, off);
    if ((t & 63) == 0) red[t >> 6] = part;
    __syncthreads();
    const float mean = (red[0] + red[1] + red[2] + red[3]) * (1.0f / 1024.0f);

    float dv[4];
#pragma unroll
    for (int i = 0; i < 4; ++i) dv[i] = xv[i] - mean;
    float p2 = dv[0] * dv[0] + dv[1] * dv[1] + dv[2] * dv[2] + dv[3] * dv[3];
#pragma unroll
    for (int off = 32; off > 0; off >>= 1) p2 += __shfl_xor(p2, off);
    if ((t & 63) == 0) red[4 + (t >> 6)] = p2;
    __syncthreads();
    const float var = (red[4] + red[5] + red[6] + red[7]) * (1.0f / 1023.0f);
    const float rden = 1.0f / (sqrtf(var) + 1e-6f);

#pragma unroll
    for (int i = 0; i < 4; ++i) {
        int j = t + i * 256;
        out[base + j] = f2b(g[j] * dv[i] * rden + bb[j]);
    }
}

// ---------------------------------------------------------------------------
// Shared epilogue.
// ---------------------------------------------------------------------------
template <int EPI>
__device__ __forceinline__ void gemm_store(int row, int col, float v,
                                           const void* res, void* out, int Ndim) {
    if (EPI == 0 || EPI == 4) {
        if (EPI == 4) v *= 0.125f;
        const int bq = row >> 11, ss = row & 2047;
        const int hh = col >> 6, dh = col & 63;
        ((u16*)out)[(((size_t)bq * HH + hh) * SS + ss) * DHH + dh] = f2b(v);
    } else if (EPI == 5) {
        const int reg = col >> 10, cc = col & 1023;
        if (reg == 0) v *= 0.125f;
        const int bq = row >> 11, ss = row & 2047;
        const int hh = cc >> 6, dh = cc & 63;
        ((u16*)out)[(size_t)reg * 4194304 +
                    (((size_t)bq * HH + hh) * SS + ss) * DHH + dh] = f2b(v);
    } else if (EPI == 1) {
        const size_t o = (size_t)row * Ndim + col;
        ((u16*)out)[o] = f2b(v + ((const float*)res)[o]);
    } else if (EPI == 2) {
        ((u16*)out)[(size_t)row * Ndim + col] = f2b(gelu_tanh_f(v));
    } else {
        const size_t o = (size_t)row * Ndim + col;
        ((float*)out)[o] = v + b2f(((const u16*)res)[o]);
    }
}

// ---------------------------------------------------------------------------
// Async-staged MFMA GEMM (round-8 verified).
// ---------------------------------------------------------------------------
template <int EPI, int TM>
__global__ __launch_bounds__(256) void gemm_as(const u16* __restrict__ A,
                                               const u16* __restrict__ BTg,
                                               const float* __restrict__ bias,
                                               const void* __restrict__ res,
                                               void* __restrict__ out,
                                               int Ndim, int Kdim) {
    constexpr int NI = (TM == 128) ? 4 : 2;
    constexpr int NCA = TM / 32;
    __shared__ __align__(16) u16 As[TM * 64];
    __shared__ __align__(16) u16 Bs[128 * 64];

    const int t = threadIdx.x;
    const int w = t >> 6, l = t & 63;
    const int lm = l & 15, lg = l >> 4;
    const int m0 = blockIdx.y * TM, n0 = blockIdx.x * 128;
    const int wro = (TM == 128) ? (w >> 1) * 64 : 0;
    const int wco = (TM == 128) ? (w & 1) * 64 : w * 32;

    f32x4 acc[4][NI];
#pragma unroll
    for (int mi = 0; mi < 4; ++mi)
#pragma unroll
        for (int ni = 0; ni < NI; ++ni) acc[mi][ni] = (f32x4){0.f, 0.f, 0.f, 0.f};

    for (int k0 = 0; k0 < Kdim; k0 += 64) {
#pragma unroll
        for (int j = 0; j < NCA; ++j) {
            const int c = (w * NCA + j) * 64 + l;
            const int r = c >> 3, g = (c & 7) ^ (r & 7);
            cp16(A + (size_t)(m0 + r) * Kdim + k0 + g * 8,
                 &As[(w * NCA + j) * 512]);
        }
#pragma unroll
        for (int j = 0; j < 4; ++j) {
            const int c = (w * 4 + j) * 64 + l;
            const int r = c >> 3, g = (c & 7) ^ (r & 7);
            cp16(BTg + (size_t)(n0 + r) * Kdim + k0 + g * 8,
                 &Bs[(w * 4 + j) * 512]);
        }
        __syncthreads();

#pragma unroll
        for (int ks = 0; ks < 64; ks += 32) {
            short8 af[4], bf[NI];
#pragma unroll
            for (int mi = 0; mi < 4; ++mi) {
                const int row = wro + mi * 16 + lm;
                af[mi] = *(const short8*)&As[row * 64 + ((ks + lg * 8) ^ ((row & 7) * 8))];
            }
#pragma unroll
            for (int ni = 0; ni < NI; ++ni) {
                const int nn = wco + ni * 16 + lm;
                bf[ni] = *(const short8*)&Bs[nn * 64 + ((ks + lg * 8) ^ ((nn & 7) * 8))];
            }
#pragma unroll
            for (int mi = 0; mi < 4; ++mi)
#pragma unroll
                for (int ni = 0; ni < NI; ++ni)
                    acc[mi][ni] = __builtin_amdgcn_mfma_f32_16x16x32_bf16(
                        af[mi], bf[ni], acc[mi][ni], 0, 0, 0);
        }
        __syncthreads();
    }

#pragma unroll
    for (int ni = 0; ni < NI; ++ni) {
        const int col = n0 + wco + ni * 16 + lm;
        const float bv = bias[col];
#pragma unroll
        for (int mi = 0; mi < 4; ++mi)
#pragma unroll
            for (int r = 0; r < 4; ++r)
                gemm_store<EPI>(m0 + wro + mi * 16 + lg * 4 + r, col,
                                acc[mi][ni][r] + bv, res, out, Ndim);
    }
}

// ---------------------------------------------------------------------------
// Fallback MFMA GEMM (W f32 on the fly) — round-5 proven.
// ---------------------------------------------------------------------------
template <int EPI, int TM>
__global__ __launch_bounds__(256) void gemm_fb(const u16* __restrict__ A,
                                               const float* __restrict__ W,
                                               const float* __restrict__ bias,
                                               const void* __restrict__ res,
                                               void* __restrict__ out,
                                               int Ndim, int Kdim) {
    constexpr int NI = (TM == 128) ? 4 : 2;
    __shared__ __align__(16) u16 As[TM * 64];
    __shared__ __align__(16) u16 BT[128 * 64];

    const int t = threadIdx.x;
    const int w = t >> 6, l = t & 63;
    const int lm = l & 15, lg = l >> 4;
    const int m0 = blockIdx.y * TM, n0 = blockIdx.x * 128;
    const int wro = (TM == 128) ? (w >> 1) * 64 : 0;
    const int wco = (TM == 128) ? (w & 1) * 64 : w * 32;

    f32x4 acc[4][NI];
#pragma unroll
    for (int mi = 0; mi < 4; ++mi)
#pragma unroll
        for (int ni = 0; ni < NI; ++ni) acc[mi][ni] = (f32x4){0.f, 0.f, 0.f, 0.f};

    const int bn = t & 127;
    const int bk4 = (t >> 7) * 4;

    for (int k0 = 0; k0 < Kdim; k0 += 64) {
#pragma unroll
        for (int it = 0; it < TM / 32; ++it) {
            int idx = it * 256 + t;
            int row = idx >> 3, c8 = (idx & 7) * 8;
            short8 v = *(const short8*)(A + (size_t)(m0 + row) * Kdim + k0 + c8);
            *(short8*)&As[row * 64 + (c8 ^ ((row & 7) * 8))] = v;
        }
#pragma unroll
        for (int it = 0; it < 8; ++it) {
            int kq = it * 8 + bk4;
            const float* wp = W + (size_t)(k0 + kq) * Ndim + n0 + bn;
            ushort4 u = {f2b(wp[0]), f2b(wp[(size_t)Ndim]),
                         f2b(wp[2 * (size_t)Ndim]), f2b(wp[3 * (size_t)Ndim])};
            *(ushort4*)&BT[bn * 64 + (kq ^ ((bn & 7) * 8))] = u;
        }
        __syncthreads();

#pragma unroll
        for (int ks = 0; ks < 64; ks += 32) {
            short8 af[4], bf[NI];
#pragma unroll
            for (int mi = 0; mi < 4; ++mi) {
                const int row = wro + mi * 16 + lm;
                af[mi] = *(const short8*)&As[row * 64 + ((ks + lg * 8) ^ ((row & 7) * 8))];
            }
#pragma unroll
            for (int ni = 0; ni < NI; ++ni) {
                const int nn = wco + ni * 16 + lm;
                bf[ni] = *(const short8*)&BT[nn * 64 + ((ks + lg * 8) ^ ((nn & 7) * 8))];
            }
#pragma unroll
            for (int mi = 0; mi < 4; ++mi)
#pragma unroll
                for (int ni = 0; ni < NI; ++ni)
                    acc[mi][ni] = __builtin_amdgcn_mfma_f32_16x16x32_bf16(
                        af[mi], bf[ni], acc[mi][ni], 0, 0, 0);
        }
        __syncthreads();
    }

#pragma unroll
    for (int ni = 0; ni < NI; ++ni) {
        const int col = n0 + wco + ni * 16 + lm;
        const float bv = bias[col];
#pragma unroll
        for (int mi = 0; mi < 4; ++mi)
#pragma unroll
            for (int r = 0; r < 4; ++r)
                gemm_store<EPI>(m0 + wro + mi * 16 + lg * 4 + r, col,
                                acc[mi][ni][r] + bv, res, out, Ndim);
    }
}

// ---------------------------------------------------------------------------
// Split-K MFMA flash attention. Block = 4 waves x 32 q; grid (S/128, H, B*2);
// blockIdx.z = b*2+half; each block processes keys [half*1024, +1024).
// Writes UNNORMALIZED O (bf16) to p0/p1 and per-q exp-sums (f32) to sume_g
// [half][b][h][s]. Merge kernel normalizes.
// ---------------------------------------------------------------------------
__global__ __launch_bounds__(256) void attn_split(const u16* __restrict__ qg,
                                                  const u16* __restrict__ kg,
                                                  const u16* __restrict__ vg,
                                                  const int* __restrict__ mask,
                                                  u16* __restrict__ p0,
                                                  u16* __restrict__ p1,
                                                  float* __restrict__ sume_g) {
    __shared__ __align__(16) u16 Ks[64 * 72];
    __shared__ __align__(16) u16 VTs[64 * 72];
    __shared__ __align__(16) float maskf[64];

    const int t = threadIdx.x;
    const int w = t >> 6;
    const int l = t & 63;
    const int lm = l & 15, lg = l >> 4;
    const int h = blockIdx.y;
    const int z = blockIdx.z;
    const int b = z >> 1, half = z & 1;
    const int qbase = blockIdx.x * 128 + w * 32;
    const size_t bhS = ((size_t)b * HH + h) * SS;
    u16* pO = half ? p1 : p0;
    const int kt0 = half * (SS / 2);

    short8 qlo[2], qhi[2];
#pragma unroll
    for (int qp = 0; qp < 2; ++qp) {
        const u16* qrow = qg + (bhS + qbase + qp * 16 + lm) * DHH + lg * 8;
        qlo[qp] = *(const short8*)qrow;
        qhi[qp] = *(const short8*)(qrow + 32);
    }

    f32x4 acc[2][4];
#pragma unroll
    for (int qp = 0; qp < 2; ++qp)
#pragma unroll
        for (int i = 0; i < 4; ++i) acc[qp][i] = (f32x4){0.f, 0.f, 0.f, 0.f};
    float sume[2] = {0.f, 0.f};

    const int kq = (t & 15) * 4, dq = (t >> 4) * 4;

    for (int kt = kt0; kt < kt0 + SS / 2; kt += 64) {
        __syncthreads();
#pragma unroll
        for (int it = 0; it < 4; ++it) {
            int idx = it * 256 + t;
            int row = idx >> 4, c4 = (idx & 15) * 4;
            ushort4 u = *(const ushort4*)(kg + (bhS + kt + row) * DHH + c4);
            *(ushort4*)&Ks[row * 72 + c4] = u;
        }
        {
            ushort4 a0 = *(const ushort4*)(vg + (bhS + kt + kq + 0) * DHH + dq);
            ushort4 a1 = *(const ushort4*)(vg + (bhS + kt + kq + 1) * DHH + dq);
            ushort4 a2 = *(const ushort4*)(vg + (bhS + kt + kq + 2) * DHH + dq);
            ushort4 a3 = *(const ushort4*)(vg + (bhS + kt + kq + 3) * DHH + dq);
            ushort4 w0 = {a0.x, a1.x, a2.x, a3.x};
            ushort4 w1 = {a0.y, a1.y, a2.y, a3.y};
            ushort4 w2 = {a0.z, a1.z, a2.z, a3.z};
            ushort4 w3 = {a0.w, a1.w, a2.w, a3.w};
            *(ushort4*)&VTs[(dq + 0) * 72 + kq] = w0;
            *(ushort4*)&VTs[(dq + 1) * 72 + kq] = w1;
            *(ushort4*)&VTs[(dq + 2) * 72 + kq] = w2;
            *(ushort4*)&VTs[(dq + 3) * 72 + kq] = w3;
        }
        if (t < 64) maskf[t] = mask[b * SS + kt + t] ? 1.0f : 0.0f;
        __syncthreads();

#pragma unroll
        for (int kb = 0; kb < 64; kb += 32) {
            short8 kfa[2], kfc[2];
#pragma unroll
            for (int s = 0; s < 2; ++s) {
                const int keyrow = kb + 8 * (lm >> 2) + 4 * s + (lm & 3);
                const u16* kr = &Ks[keyrow * 72 + lg * 8];
                kfa[s] = *(const short8*)kr;
                kfc[s] = *(const short8*)(kr + 32);
            }
            short8 p8[2];
#pragma unroll
            for (int qp = 0; qp < 2; ++qp) {
                float ev[8];
#pragma unroll
                for (int s = 0; s < 2; ++s) {
                    f32x4 c = (f32x4){0.f, 0.f, 0.f, 0.f};
                    c = __builtin_amdgcn_mfma_f32_16x16x32_bf16(kfa[s], qlo[qp], c, 0, 0, 0);
                    c = __builtin_amdgcn_mfma_f32_16x16x32_bf16(kfc[s], qhi[qp], c, 0, 0, 0);
                    const float4 mv = *(const float4*)&maskf[kb + 8 * lg + 4 * s];
                    float e0 = __expf(c[0]) * mv.x;
                    float e1 = __expf(c[1]) * mv.y;
                    float e2 = __expf(c[2]) * mv.z;
                    float e3 = __expf(c[3]) * mv.w;
                    sume[qp] += e0 + e1 + e2 + e3;
                    ev[4 * s + 0] = e0; ev[4 * s + 1] = e1;
                    ev[4 * s + 2] = e2; ev[4 * s + 3] = e3;
                }
#pragma unroll
                for (int i = 0; i < 8; ++i)
                    p8[qp][i] = (short)(__float_as_uint(ev[i]) >> 16);
            }
#pragma unroll
            for (int d0 = 0; d0 < 4; ++d0) {
                const short8 v8 = *(const short8*)&VTs[(d0 * 16 + lm) * 72 + kb + lg * 8];
#pragma unroll
                for (int qp = 0; qp < 2; ++qp)
                    acc[qp][d0] = __builtin_amdgcn_mfma_f32_16x16x32_bf16(
                        p8[qp], v8, acc[qp][d0], 0, 0, 0);
            }
        }
    }

#pragma unroll
    for (int qp = 0; qp < 2; ++qp) {
        float s = sume[qp];
        s += __shfl_xor(s, 16);
        s += __shfl_xor(s, 32);
        if (l < 16)   // one writer per q-row (sum replicated across lane groups)
            sume_g[(size_t)half * (BB * HH * SS) + bhS + qbase + qp * 16 + lm] = s;
#pragma unroll
        for (int d0 = 0; d0 < 4; ++d0)
#pragma unroll
            for (int r = 0; r < 4; ++r) {
                const int q = qbase + qp * 16 + 4 * lg + r;
                pO[(size_t)(b * SS + q) * DD + h * DHH + d0 * 16 + lm] =
                    f2b(acc[qp][d0][r]);
            }
    }
}

// Merge: hid = (p0 + p1) / (s0 + s1). hid aliases p0 (same-index RMW, safe).
__global__ __launch_bounds__(256) void attn_merge(const u16* __restrict__ p1,
                                                  const float* __restrict__ sume_g,
                                                  u16* __restrict__ hid) {
    const int row = blockIdx.x;
    const int b = row >> 11, s = row & 2047;
    const int t = threadIdx.x;
#pragma unroll
    for (int i = 0; i < 4; ++i) {
        const int j = t + i * 256;
        const int h = j >> 6;
        const size_t si = ((size_t)b * HH + h) * SS + s;
        const float d = sume_g[si] + sume_g[(size_t)BB * HH * SS + si];
        const size_t o = (size_t)row * DD + j;
        hid[o] = f2b((b2f(hid[o]) + b2f(p1[o])) / d);
    }
}

// ---------------------------------------------------------------------------
// Round-6 attention (for the small-ws fallback path).
// ---------------------------------------------------------------------------
__global__ __launch_bounds__(256) void attn_mfma2(const u16* __restrict__ qg,
                                                  const u16* __restrict__ kg,
                                                  const u16* __restrict__ vg,
                                                  const int* __restrict__ mask,
                                                  u16* __restrict__ hid) {
    __shared__ __align__(16) u16 Ks[64 * 72];
    __shared__ __align__(16) u16 VTs[64 * 72];
    __shared__ __align__(16) float maskf[64];

    const int t = threadIdx.x;
    const int w = t >> 6;
    const int l = t & 63;
    const int lm = l & 15, lg = l >> 4;
    const int h = blockIdx.y, b = blockIdx.z;
    const int qbase = blockIdx.x * 128 + w * 32;
    const size_t bhS = ((size_t)b * HH + h) * SS;

    short8 qlo[2], qhi[2];
#pragma unroll
    for (int qp = 0; qp < 2; ++qp) {
        const u16* qrow = qg + (bhS + qbase + qp * 16 + lm) * DHH + lg * 8;
        qlo[qp] = *(const short8*)qrow;
        qhi[qp] = *(const short8*)(qrow + 32);
    }

    f32x4 acc[2][4];
#pragma unroll
    for (int qp = 0; qp < 2; ++qp)
#pragma unroll
        for (int i = 0; i < 4; ++i) acc[qp][i] = (f32x4){0.f, 0.f, 0.f, 0.f};
    float sume[2] = {0.f, 0.f};

    const int kq = (t & 15) * 4, dq = (t >> 4) * 4;

    for (int kt = 0; kt < SS; kt += 64) {
        __syncthreads();
#pragma unroll
        for (int it = 0; it < 4; ++it) {
            int idx = it * 256 + t;
            int row = idx >> 4, c4 = (idx & 15) * 4;
            ushort4 u = *(const ushort4*)(kg + (bhS + kt + row) * DHH + c4);
            *(ushort4*)&Ks[row * 72 + c4] = u;
        }
        {
            ushort4 a0 = *(const ushort4*)(vg + (bhS + kt + kq + 0) * DHH + dq);
            ushort4 a1 = *(const ushort4*)(vg + (bhS + kt + kq + 1) * DHH + dq);
            ushort4 a2 = *(const ushort4*)(vg + (bhS + kt + kq + 2) * DHH + dq);
            ushort4 a3 = *(const ushort4*)(vg + (bhS + kt + kq + 3) * DHH + dq);
            ushort4 w0 = {a0.x, a1.x, a2.x, a3.x};
            ushort4 w1 = {a0.y, a1.y, a2.y, a3.y};
            ushort4 w2 = {a0.z, a1.z, a2.z, a3.z};
            ushort4 w3 = {a0.w, a1.w, a2.w, a3.w};
            *(ushort4*)&VTs[(dq + 0) * 72 + kq] = w0;
            *(ushort4*)&VTs[(dq + 1) * 72 + kq] = w1;
            *(ushort4*)&VTs[(dq + 2) * 72 + kq] = w2;
            *(ushort4*)&VTs[(dq + 3) * 72 + kq] = w3;
        }
        if (t < 64) maskf[t] = mask[b * SS + kt + t] ? 1.0f : 0.0f;
        __syncthreads();

#pragma unroll
        for (int kb = 0; kb < 64; kb += 32) {
            short8 kfa[2], kfc[2];
#pragma unroll
            for (int s = 0; s < 2; ++s) {
                const int keyrow = kb + 8 * (lm >> 2) + 4 * s + (lm & 3);
                const u16* kr = &Ks[keyrow * 72 + lg * 8];
                kfa[s] = *(const short8*)kr;
                kfc[s] = *(const short8*)(kr + 32);
            }
            short8 p8[2];
#pragma unroll
            for (int qp = 0; qp < 2; ++qp) {
                float ev[8];
#pragma unroll
                for (int s = 0; s < 2; ++s) {
                    f32x4 c = (f32x4){0.f, 0.f, 0.f, 0.f};
                    c = __builtin_amdgcn_mfma_f32_16x16x32_bf16(kfa[s], qlo[qp], c, 0, 0, 0);
                    c = __builtin_amdgcn_mfma_f32_16x16x32_bf16(kfc[s], qhi[qp], c, 0, 0, 0);
                    const float4 mv = *(const float4*)&maskf[kb + 8 * lg + 4 * s];
                    float e0 = __expf(c[0]) * mv.x;
                    float e1 = __expf(c[1]) * mv.y;
                    float e2 = __expf(c[2]) * mv.z;
                    float e3 = __expf(c[3]) * mv.w;
                    sume[qp] += e0 + e1 + e2 + e3;
                    ev[4 * s + 0] = e0; ev[4 * s + 1] = e1;
                    ev[4 * s + 2] = e2; ev[4 * s + 3] = e3;
                }
#pragma unroll
                for (int i = 0; i < 8; ++i)
                    p8[qp][i] = (short)(__float_as_uint(ev[i]) >> 16);
            }
#pragma unroll
            for (int d0 = 0; d0 < 4; ++d0) {
                const short8 v8 = *(const short8*)&VTs[(d0 * 16 + lm) * 72 + kb + lg * 8];
#pragma unroll
                for (int qp = 0; qp < 2; ++qp)
                    acc[qp][d0] = __builtin_amdgcn_mfma_f32_16x16x32_bf16(
                        p8[qp], v8, acc[qp][d0], 0, 0, 0);
            }
        }
    }

#pragma unroll
    for (int qp = 0; qp < 2; ++qp) {
        float s = sume[qp];
        s += __shfl_xor(s, 16);
        s += __shfl_xor(s, 32);
        float rinv[4];
#pragma unroll
        for (int r = 0; r < 4; ++r) rinv[r] = 1.0f / __shfl(s, 4 * lg + r);
#pragma unroll
        for (int d0 = 0; d0 < 4; ++d0)
#pragma unroll
            for (int r = 0; r < 4; ++r) {
                const int q = qbase + qp * 16 + 4 * lg + r;
                hid[(size_t)(b * SS + q) * DD + h * DHH + d0 * 16 + lm] =
                    f2b(acc[qp][d0][r] * rinv[r]);
            }
    }
}

// ---------------------------------------------------------------------------
extern "C" void kernel_launch(void* const* d_in, const int* in_sizes, int n_in,
                              void* d_out, int out_size, void* d_ws, size_t ws_size,
                              hipStream_t stream) {
    (void)in_sizes; (void)n_in; (void)out_size;

    const float* hidden = (const float*)d_in[0];
    const int*   mask   = (const int*)d_in[1];
    const float* wq = (const float*)d_in[2];  const float* bq = (const float*)d_in[3];
    const float* wk = (const float*)d_in[4];  const float* bk = (const float*)d_in[5];
    const float* wv = (const float*)d_in[6];  const float* bv = (const float*)d_in[7];
    const float* wo = (const float*)d_in[8];  const float* bo = (const float*)d_in[9];
    const float* w1 = (const float*)d_in[10]; const float* b1 = (const float*)d_in[11];
    const float* w2 = (const float*)d_in[12]; const float* b2 = (const float*)d_in[13];
    const float* ln1g = (const float*)d_in[14]; const float* ln1b = (const float*)d_in[15];
    const float* ln2g = (const float*)d_in[16]; const float* ln2b = (const float*)d_in[17];

    // Activation regions (bf16), recycled:
    //   R0: xln -> attn-p0 -> hidb -> ffin   R1: q -> ffh(lo)
    //   R2: k -> ffh(hi)                     R3: v -> h
    char* ws = (char*)d_ws;
    u16* R0 = (u16*)(ws + 0);
    u16* R1 = (u16*)(ws + 8388608);
    u16* R2 = (u16*)(ws + 16777216);
    u16* R3 = (u16*)(ws + 25165824);
    float* outp = (float*)d_out;

    // Weight pool: qkvT 6 | woT 2 | w1T 8 | w2T 8 MB | bqkv 16 KB.
    // w1T's region doubles as attention partial p1 (wo/w1 converted AFTER merge).
    const size_t WTOFF = 33554432;
    const bool big = ws_size >= WTOFF + 25165824 + 16384;

    if (big) {
        u16* qkvT = (u16*)(ws + WTOFF);                  // [3072,1024] bf16
        u16* woT  = (u16*)(ws + WTOFF + 6291456);        // [1024,1024]
        u16* w1T  = (u16*)(ws + WTOFF + 8388608);        // [4096,1024]  (= p1 first)
        u16* w2T  = (u16*)(ws + WTOFF + 16777216);       // [1024,4096]
        float* bqkv = (float*)(ws + WTOFF + 25165824);   // 3072 f32
        u16* p1 = w1T;                                   // 8 MB partial (pre-w1T)
        float* sume_g = (float*)d_out;                   // 512 KB scratch in d_out

        // 0. upfront conversions (qkv fused + w2) + bias pack
        wconvA<<<1792, 256, 0, stream>>>(wq, wk, wv, w2, qkvT, w2T);
        pack3<<<12, 256, 0, stream>>>(bq, bk, bv, bqkv);

        // 1. LN1 -> R0
        ln_kernel<float><<<MM, 256, 0, stream>>>(hidden, ln1g, ln1b, R0);
        // 2. fused QKV (N=3072) -> R1/R2/R3
        gemm_as<5, 128><<<dim3(3072 / 128, MM / 128), 256, 0, stream>>>(
            R0, qkvT, bqkv, nullptr, R1, 3072, DD);
        // 3. split-K attention -> partials (p0=R0, p1=w1T region), then merge
        attn_split<<<dim3(SS / 128, HH, BB * 2), 256, 0, stream>>>(
            R1, R2, R3, mask, R0, p1, sume_g);
        attn_merge<<<MM, 256, 0, stream>>>(p1, sume_g, R0);
        // 4. deferred conversions (wo, w1) — their regions are now free
        wconvB<<<1280, 256, 0, stream>>>(wo, w1, woT, w1T);
        // 5. out-proj + f32 residual -> h(R3)
        gemm_as<1, 128><<<dim3(DD / 128, MM / 128), 256, 0, stream>>>(
            R0, woT, bo, hidden, R3, DD, DD);
        // 6. LN2 -> ffin(R0)
        ln_kernel<u16><<<MM, 256, 0, stream>>>(R3, ln2g, ln2b, R0);
        // 7. FFN in 2 strips of 2048 rows; ffh spans R1+R2
        for (int s2 = 0; s2 < 2; ++s2) {
            const size_t r0 = (size_t)s2 * 2048;
            gemm_as<2, 128><<<dim3(DFF / 128, 2048 / 128), 256, 0, stream>>>(
                R0 + r0 * DD, w1T, b1, nullptr, R1, DFF, DD);
            gemm_as<3, 64><<<dim3(DD / 128, 2048 / 64), 256, 0, stream>>>(
                R1, w2T, b2, R3 + r0 * DD, outp + r0 * DD, DD, DFF);
        }
    } else {
        // Fallback: on-the-fly weight conversion (round-5 engine)
        ln_kernel<float><<<MM, 256, 0, stream>>>(hidden, ln1g, ln1b, R0);
        gemm_fb<4, 128><<<dim3(DD / 128, MM / 128), 256, 0, stream>>>(R0, wq, bq, nullptr, R1, DD, DD);
        gemm_fb<0, 128><<<dim3(DD / 128, MM / 128), 256, 0, stream>>>(R0, wk, bk, nullptr, R2, DD, DD);
        gemm_fb<0, 128><<<dim3(DD / 128, MM / 128), 256, 0, stream>>>(R0, wv, bv, nullptr, R3, DD, DD);
        attn_mfma2<<<dim3(SS / 128, HH, BB), 256, 0, stream>>>(R1, R2, R3, mask, R0);
        gemm_fb<1, 128><<<dim3(DD / 128, MM / 128), 256, 0, stream>>>(R0, wo, bo, hidden, R3, DD, DD);
        ln_kernel<u16><<<MM, 256, 0, stream>>>(R3, ln2g, ln2b, R0);
        for (int s2 = 0; s2 < 2; ++s2) {
            const size_t r0 = (size_t)s2 * 2048;
            gemm_fb<2, 128><<<dim3(DFF / 128, 2048 / 128), 256, 0, stream>>>(
                R0 + r0 * DD, w1, b1, nullptr, R1, DFF, DD);
            gemm_fb<3, 64><<<dim3(DD / 128, 2048 / 64), 256, 0, stream>>>(
                R1, w2, b2, R3 + r0 * DD, outp + r0 * DD, DD, DFF);
        }
    }
}